// Round 4
// baseline (28.135 us; speedup 1.0000x reference)
//
#include <hip/hip_runtime.h>
#include <hip/hip_bf16.h>

#define TCTX 500
#define DFEAT 8192
#define BD 16          // full output rows per block (16*2000B = 32000B, 64B-aligned)
#define LDS_S 500      // floats per staged h-row (2000B, 16B-aligned)

typedef float v4f __attribute__((ext_vector_type(4)));

__global__ __launch_bounds__(512) void MegaMerge_77283641524594_kernel(
    const float* __restrict__ h,
    const float* __restrict__ c2q,
    const float* __restrict__ q2c,
    float* __restrict__ out)
{
    // h tile staged transposed: hs[d_local * LDS_S + t]
    __shared__ float hs[BD * LDS_S];   // 32000 B

    const int tid = threadIdx.x;
    const int d0  = blockIdx.x * BD;

    // Store-phase mapping: 512 thr = 4 row-groups x 128 t4-lanes.
    const int t4   = tid & 127;         // float4 index along t (0..124 active)
    const int rowg = tid >> 7;          // 0..3; rows rowg, rowg+4, rowg+8, rowg+12
    const bool act = (t4 < 125);        // 125 * 4 = 500 = TCTX

    // ---- Prefetch c2q / q2c into registers (cached loads: L3-resident) ----
    v4f cpre[4], qpre[4];
    if (act) {
        #pragma unroll
        for (int k = 0; k < 4; ++k) {
            const size_t j = (size_t)(d0 + rowg + 4 * k);
            cpre[k] = *reinterpret_cast<const v4f*>(&c2q[j * TCTX + t4 * 4]);
            qpre[k] = *reinterpret_cast<const v4f*>(&q2c[j * TCTX + t4 * 4]);
        }
    }

    // ---- Stage h[t, d0:d0+16] transposed into LDS ----
    {
        const int dc = (tid & 3) * 4;   // 0,4,8,12
        const int tr = tid >> 2;        // 0..127
        #pragma unroll
        for (int p = 0; p < 4; ++p) {
            const int t = p * 128 + tr;
            if (t < TCTX) {
                const v4f v = *reinterpret_cast<const v4f*>(
                    &h[(size_t)t * DFEAT + d0 + dc]);
                hs[(dc + 0) * LDS_S + t] = v.x;   // 2-way bank aliasing max (free)
                hs[(dc + 1) * LDS_S + t] = v.y;
                hs[(dc + 2) * LDS_S + t] = v.z;
                hs[(dc + 3) * LDS_S + t] = v.w;
            }
        }
    }
    __syncthreads();

    // ---- Store phase: nontemporal (streaming) writes — out is write-once ----
    if (act) {
        const size_t sec = (size_t)DFEAT * TCTX;
        #pragma unroll
        for (int k = 0; k < 4; ++k) {
            const int dl = rowg + 4 * k;
            const size_t j = (size_t)(d0 + dl);
            const v4f hv = *reinterpret_cast<const v4f*>(
                &hs[dl * LDS_S + t4 * 4]);      // linear 16B/lane: conflict-free
            const v4f c = cpre[k];
            const v4f q = qpre[k];
            const v4f hc = hv * c;
            const v4f hq = hv * q;
            const size_t o = j * TCTX + t4 * 4;
            __builtin_nontemporal_store(hv, reinterpret_cast<v4f*>(&out[o          ]));
            __builtin_nontemporal_store(c,  reinterpret_cast<v4f*>(&out[o + sec    ]));
            __builtin_nontemporal_store(hc, reinterpret_cast<v4f*>(&out[o + 2 * sec]));
            __builtin_nontemporal_store(hq, reinterpret_cast<v4f*>(&out[o + 3 * sec]));
        }
    }
}

extern "C" void kernel_launch(void* const* d_in, const int* in_sizes, int n_in,
                              void* d_out, int out_size, void* d_ws, size_t ws_size,
                              hipStream_t stream) {
    const float* h   = (const float*)d_in[0];
    const float* c2q = (const float*)d_in[1];
    const float* q2c = (const float*)d_in[2];
    float* out = (float*)d_out;

    dim3 grid(DFEAT / BD);   // 512 blocks, each owns 16 complete output rows
    dim3 block(512);
    MegaMerge_77283641524594_kernel<<<grid, block, 0, stream>>>(h, c2q, q2c, out);
}

// Round 5
// 26.736 us; speedup vs baseline: 1.0523x; 1.0523x over previous
//
#include <hip/hip_runtime.h>
#include <hip/hip_bf16.h>

#define TCTX 500
#define DFEAT 8192
#define BD 16                 // output rows per block
#define TT 128                // t-values per block
#define LDS_S (TT + 4)        // padded stride (floats)

typedef float v4f __attribute__((ext_vector_type(4)));

__global__ __launch_bounds__(256) void MegaMerge_77283641524594_kernel(
    const float* __restrict__ h,
    const float* __restrict__ c2q,
    const float* __restrict__ q2c,
    float* __restrict__ out)
{
    __shared__ float hs[BD * LDS_S];   // 8448 B -> 8 blocks/CU, 32 waves/CU

    const int tid = threadIdx.x;
    const int d0  = blockIdx.x * BD;
    const int t0  = blockIdx.y * TT;

    // Store-phase mapping: 256 thr = 8 row-groups x 32 t4-lanes.
    const int t4   = tid & 31;          // float4 index along t within tile
    const int rowg = tid >> 5;          // 0..7 -> rows 2*rowg, 2*rowg+1
    const int t    = t0 + t4 * 4;
    const bool act = (t < TCTX);        // 500 % 4 == 0 -> full float4 when true

    // ---- Prefetch c2q / q2c (independent of LDS; issues before barrier) ----
    v4f cpre[2], qpre[2];
    if (act) {
        #pragma unroll
        for (int k = 0; k < 2; ++k) {
            const size_t j = (size_t)(d0 + rowg * 2 + k);
            cpre[k] = *reinterpret_cast<const v4f*>(&c2q[j * TCTX + t]);
            qpre[k] = *reinterpret_cast<const v4f*>(&q2c[j * TCTX + t]);
        }
    }

    // ---- Stage h[t, d0:d0+16] transposed into LDS ----
    // 4 lanes x float4 cover 16 d-floats; 64 t-rows per pass; 2 passes.
    {
        const int dc = (tid & 3) * 4;   // 0,4,8,12
        const int tr = tid >> 2;        // 0..63
        #pragma unroll
        for (int p = 0; p < 2; ++p) {
            const int tl = p * 64 + tr;
            const int tg = t0 + tl;
            if (tg < TCTX) {
                const v4f v = *reinterpret_cast<const v4f*>(
                    &h[(size_t)tg * DFEAT + d0 + dc]);
                hs[(dc + 0) * LDS_S + tl] = v.x;   // 2-way aliasing max (free)
                hs[(dc + 1) * LDS_S + tl] = v.y;
                hs[(dc + 2) * LDS_S + tl] = v.z;
                hs[(dc + 3) * LDS_S + tl] = v.w;
            }
        }
    }
    __syncthreads();

    // ---- Store phase: cached float4 writes, 1KB/wave per section ----
    if (act) {
        const size_t sec = (size_t)DFEAT * TCTX;
        #pragma unroll
        for (int k = 0; k < 2; ++k) {
            const int dl = rowg * 2 + k;
            const size_t j = (size_t)(d0 + dl);
            const v4f hv = *reinterpret_cast<const v4f*>(
                &hs[dl * LDS_S + t4 * 4]);
            const v4f c = cpre[k];
            const v4f q = qpre[k];
            const v4f hc = hv * c;
            const v4f hq = hv * q;
            const size_t o = j * TCTX + t;
            *reinterpret_cast<v4f*>(&out[o          ]) = hv;  // H^T
            *reinterpret_cast<v4f*>(&out[o + sec    ]) = c;   // c2q copy
            *reinterpret_cast<v4f*>(&out[o + 2 * sec]) = hc;  // H*C
            *reinterpret_cast<v4f*>(&out[o + 3 * sec]) = hq;  // H*Q
        }
    }
}

extern "C" void kernel_launch(void* const* d_in, const int* in_sizes, int n_in,
                              void* d_out, int out_size, void* d_ws, size_t ws_size,
                              hipStream_t stream) {
    const float* h   = (const float*)d_in[0];
    const float* c2q = (const float*)d_in[1];
    const float* q2c = (const float*)d_in[2];
    float* out = (float*)d_out;

    dim3 grid(DFEAT / BD, (TCTX + TT - 1) / TT);  // 512 x 4 = 2048 blocks
    dim3 block(256);                               // 8 blocks/CU -> 32 waves/CU
    MegaMerge_77283641524594_kernel<<<grid, block, 0, stream>>>(h, c2q, q2c, out);
}